// Round 6
// baseline (126.728 us; speedup 1.0000x reference)
//
#include <hip/hip_runtime.h>
#include <math.h>

#define A_N   8732
#define C_N   81
#define B_N   32
#define NCLS  80
#define NTASK (B_N * NCLS)
#define TOPK  100
#define NTHR  256
#define BINS  2048
#define SH    21              // 32 - 11 bits -> 2048 bins
#define CAND  512
#define TA    64
#define NV4   2183            // A_N / 4
#define KPT   9               // ceil(NV4 / NTHR) uint4 per thread

// ln(3/7) in f64: sigmoid_f64(x) > 0.3  <=>  x > THR_LOGIT
#define THR_LOGIT (-0.8472978603872034)

// Monotone map: float bits -> unsigned, order-preserving. 0 = invalid sentinel.
__device__ __forceinline__ unsigned mapf(float x) {
    unsigned b = __float_as_uint(x);
    return b ^ ((b & 0x80000000u) ? 0xFFFFFFFFu : 0x80000000u);
}
__device__ __forceinline__ float unmapf(unsigned u) {
    unsigned b = (u & 0x80000000u) ? (u ^ 0x80000000u) : ~u;
    return __uint_as_float(b);
}

// Wave-aggregated shared-counter append: one atomic per wave instead of per lane.
__device__ __forceinline__ void append_cand(bool pred, unsigned key, unsigned idx,
                                            int* counter, unsigned long long* cnd) {
    unsigned long long mask = __ballot(pred);
    if (mask == 0ull) return;
    int lane = threadIdx.x & 63;
    int lower = (int)__popcll(mask & ((1ull << lane) - 1ull));
    int leader = __ffsll((unsigned long long)mask) - 1;
    int base = 0;
    if (lane == leader) base = atomicAdd(counter, (int)__popcll(mask));
    base = __shfl(base, leader);
    if (pred) {
        int p = base + lower;
        if (p < CAND) cnd[p] = ((unsigned long long)key << 32) | (unsigned)(~idx);
    }
}

// ---- Kernel T: coalesced logits read, keys transposed to (B, 80, A) ----
__global__ __launch_bounds__(NTHR) void key_transpose_kernel(
    const float* __restrict__ logits,    // (B, A, 81)
    unsigned* __restrict__ keys)         // (B, 80, A)
{
    __shared__ unsigned tile[NCLS][TA + 1];   // 80 x 65 words = 20.8 KB
    const int NT = (A_N + TA - 1) / TA;       // 137
    const int b  = blockIdx.x / NT;
    const int t0 = blockIdx.x % NT;
    const int a0 = t0 * TA;
    const int an = min(TA, A_N - a0);
    const int tid = threadIdx.x;

    const float* src = logits + ((size_t)b * A_N + a0) * C_N;

    if (an == TA) {
        const float4* src4 = (const float4*)src;
        const int total4 = TA * C_N / 4;      // 1296
        for (int i = tid; i < total4; i += NTHR) {
            float4 v = src4[i];
            int base = 4 * i;
            int r  = base / C_N;
            int ch = base - r * C_N;
            float xs[4] = { v.x, v.y, v.z, v.w };
            #pragma unroll
            for (int k = 0; k < 4; ++k) {
                if (ch > 0)
                    tile[ch - 1][r] = ((double)xs[k] > THR_LOGIT) ? mapf(xs[k]) : 0u;
                if (++ch == C_N) { ch = 0; ++r; }
            }
        }
        __syncthreads();
        const int R4 = TA / 4;                // 16 uint4 per class row
        for (int i = tid; i < NCLS * R4; i += NTHR) {
            int row = i >> 4, j = i & (R4 - 1);
            uint4 w;
            w.x = tile[row][4 * j + 0];
            w.y = tile[row][4 * j + 1];
            w.z = tile[row][4 * j + 2];
            w.w = tile[row][4 * j + 3];
            *(uint4*)(keys + ((size_t)b * NCLS + row) * A_N + a0 + 4 * j) = w;
        }
    } else {
        const int total = an * C_N;
        for (int i = tid; i < total; i += NTHR) {
            int r = i / C_N, ch = i - r * C_N;
            float x = src[i];
            if (ch > 0)
                tile[ch - 1][r] = ((double)x > THR_LOGIT) ? mapf(x) : 0u;
        }
        __syncthreads();
        for (int i = tid; i < NCLS * an; i += NTHR) {
            int row = i / an, col = i - row * an;
            keys[((size_t)b * NCLS + row) * A_N + a0 + col] = tile[row][col];
        }
    }
}

// ---- Kernel M: one task per block; register-staged keys, single global pass ----
template<bool USE_WS>
__global__ __launch_bounds__(NTHR) void ssd_nms_kernel(
    const float* __restrict__ logits,
    const unsigned* __restrict__ keys,
    const float* __restrict__ boxreg,
    const float* __restrict__ priors,
    float* __restrict__ out)
{
    const int task = blockIdx.x;
    const int b = task / NCLS;
    const int c = task % NCLS;
    const int tid = threadIdx.x;

    __shared__ unsigned hist[BINS];               // 8 KB
    __shared__ unsigned wtot[4];
    __shared__ unsigned long long cand[CAND];     // 4 KB
    __shared__ unsigned long long ssel[TOPK];
    __shared__ double sb0[TOPK], sb1[TOPK], sb2[TOPK], sb3[TOPK];
    __shared__ double sarea[TOPK], sscore[TOPK];
    __shared__ float fb0[TOPK], fb1[TOPK], fb2[TOPK], fb3[TOPK], farea[TOPK];
    __shared__ int svalid[TOPK];
    __shared__ unsigned long long supmask[TOPK][2];
    __shared__ unsigned long long keepw[2];
    __shared__ int scal[2];

    // ---- issue ALL key loads up front (independent, deep in-flight queue)
    uint4 kreg[KPT];
    if (USE_WS) {
        const uint4* src = (const uint4*)(keys + ((size_t)b * NCLS + c) * A_N);
        #pragma unroll
        for (int j = 0; j < KPT; ++j) {
            int i = tid + j * NTHR;
            if (i < NV4) kreg[j] = src[i];
            else         kreg[j] = make_uint4(0u, 0u, 0u, 0u);
        }
    }

    for (int k = tid; k < BINS; k += NTHR) hist[k] = 0;
    for (int i = tid; i < CAND; i += NTHR) cand[i] = 0ull;
    if (tid < TOPK) ssel[tid] = 0ull;
    if (tid == 0) { scal[0] = 0; scal[1] = 1; }
    __syncthreads();

    if (USE_WS) {
        // Force all loads live here: compiler must issue them back-to-back above.
        #pragma unroll
        for (int j = 0; j < KPT; ++j)
            asm volatile("" : "+v"(kreg[j].x), "+v"(kreg[j].y),
                              "+v"(kreg[j].z), "+v"(kreg[j].w));
    }

    const float* lg = logits + ((size_t)b * A_N * C_N) + (c + 1);

    // ---- Pass A: 2048-bin histogram (from registers when USE_WS)
    if (USE_WS) {
        #pragma unroll
        for (int j = 0; j < KPT; ++j) {
            uint4 v = kreg[j];
            if (v.x) atomicAdd(&hist[v.x >> SH], 1u);
            if (v.y) atomicAdd(&hist[v.y >> SH], 1u);
            if (v.z) atomicAdd(&hist[v.z >> SH], 1u);
            if (v.w) atomicAdd(&hist[v.w >> SH], 1u);
        }
    } else {
        for (int a = tid; a < A_N; a += NTHR) {
            float x = lg[(size_t)a * C_N];
            if ((double)x > THR_LOGIT) atomicAdd(&hist[mapf(x) >> SH], 1u);
        }
    }
    __syncthreads();

    // ---- cutoff via wave-level suffix scan (2 barriers total)
    {
        unsigned s = 0;
        #pragma unroll
        for (int k = 0; k < BINS / NTHR; ++k) s += hist[tid * (BINS / NTHR) + k];
        unsigned incl = s;
        int lane = tid & 63;
        #pragma unroll
        for (int off = 1; off < 64; off <<= 1) {
            unsigned v = __shfl_down(incl, off);
            if (lane + off < 64) incl += v;     // incl = sum over lanes >= lane
        }
        if (lane == 0) wtot[tid >> 6] = incl;   // wave total
        __syncthreads();
        unsigned hi = 0;
        #pragma unroll
        for (int w = 0; w < 4; ++w) if (w > (tid >> 6)) hi += wtot[w];
        unsigned excl = hi + (incl - s);        // sum over threads > tid
        if (excl < TOPK && excl + s >= TOPK) {  // unique crossing thread
            unsigned running = excl;
            #pragma unroll
            for (int k = BINS / NTHR - 1; k >= 0; --k) {
                running += hist[tid * (BINS / NTHR) + k];
                if (running >= TOPK) {
                    scal[1] = (int)(((unsigned)(tid * (BINS / NTHR) + k)) << SH);
                    break;
                }
            }
        }
    }
    __syncthreads();
    const unsigned cutoff = (unsigned)scal[1];   // >= 1 always

    // ---- Pass B: gather candidates >= cutoff from REGISTERS, wave-aggregated
    if (USE_WS) {
        #pragma unroll
        for (int j = 0; j < KPT; ++j) {
            uint4 v = kreg[j];
            int a4 = 4 * (tid + j * NTHR);       // OOB lanes hold 0 -> pred false
            append_cand(v.x >= cutoff, v.x, (unsigned)(a4 + 0), &scal[0], cand);
            append_cand(v.y >= cutoff, v.y, (unsigned)(a4 + 1), &scal[0], cand);
            append_cand(v.z >= cutoff, v.z, (unsigned)(a4 + 2), &scal[0], cand);
            append_cand(v.w >= cutoff, v.w, (unsigned)(a4 + 3), &scal[0], cand);
        }
    } else {
        for (int a = tid; a < A_N; a += NTHR) {
            float x = lg[(size_t)a * C_N];
            if ((double)x > THR_LOGIT) {
                unsigned u = mapf(x);
                if (u >= cutoff) {
                    int p = atomicAdd(&scal[0], 1);
                    if (p < CAND) cand[p] = ((unsigned long long)u << 32) | (unsigned)(~(unsigned)a);
                }
            }
        }
    }
    __syncthreads();

    // ---- exact rank via all-pairs over the M gathered (bounded)
    {
        int M = scal[0]; if (M > CAND) M = CAND;
        int Mr = (M + 7) & ~7;
        for (int i = tid; i < Mr; i += NTHR) {
            unsigned long long mykey = cand[i];
            int rank = 0;
            #pragma unroll 8
            for (int j = 0; j < Mr; ++j) rank += (cand[j] > mykey) ? 1 : 0;
            if (mykey != 0ull && rank < TOPK) ssel[rank] = mykey;
        }
    }
    __syncthreads();

    // ---- decode top-100 boxes in f64 (reference op order) + f32 shadows
    if (tid < TOPK) {
        unsigned long long key = ssel[tid];
        int valid = (key != 0ull);
        double b0 = 0, b1 = 0, b2 = 0, b3 = 0, area = 0, sc = 0;
        if (valid) {
            int a = (int)(~(unsigned)key);
            float x = unmapf((unsigned)(key >> 32));
            sc = 1.0 / (1.0 + exp(-(double)x));
            float4 r4 = *(const float4*)(boxreg + ((size_t)b * A_N + a) * 4);
            float4 p4 = *(const float4*)(priors + (size_t)a * 4);
            double ty = (double)r4.x / 10.0;
            double tx = (double)r4.y / 10.0;
            double th = (double)r4.z / 5.0;
            double tw = (double)r4.w / 5.0;
            double py = (double)p4.x, px = (double)p4.y;
            double ph = (double)p4.z, pw = (double)p4.w;
            double cy = ty * ph + py;
            double cx = tx * pw + px;
            double hh = exp(th) * ph;
            double ww = exp(tw) * pw;
            b0 = cy - hh / 2.0; b1 = cx - ww / 2.0;
            b2 = cy + hh / 2.0; b3 = cx + ww / 2.0;
            double e0 = b2 - b0; if (e0 < 0.0) e0 = 0.0;
            double e1 = b3 - b1; if (e1 < 0.0) e1 = 0.0;
            area = e0 * e1;
        }
        sb0[tid] = b0; sb1[tid] = b1; sb2[tid] = b2; sb3[tid] = b3;
        sarea[tid] = area; sscore[tid] = sc;
        fb0[tid] = (float)b0; fb1[tid] = (float)b1;
        fb2[tid] = (float)b2; fb3[tid] = (float)b3;
        farea[tid] = (float)area;
        svalid[tid] = valid;
    }
    __syncthreads();

    // ---- suppression bitmask: f32 screen, exact-f64 only in the +-1e-3 window
    if (tid < 2 * TOPK) {
        int i = tid >> 1, w = tid & 1;
        unsigned long long m = 0;
        if (svalid[i]) {
            float i0 = fb0[i], i1 = fb1[i], i2 = fb2[i], i3 = fb3[i], ia = farea[i];
            int jbase = w * 64;
            int jend = min(jbase + 64, TOPK);
            int jstart = (jbase > i + 1) ? jbase : (i + 1);
            for (int j = jstart; j < jend; ++j) {
                float tl0 = fmaxf(i0, fb0[j]);
                float tl1 = fmaxf(i1, fb1[j]);
                float br0 = fminf(i2, fb2[j]);
                float br1 = fminf(i3, fb3[j]);
                float wh0 = fmaxf(br0 - tl0, 0.0f);
                float wh1 = fmaxf(br1 - tl1, 0.0f);
                float inter = wh0 * wh1;
                float denom = (ia + farea[j]) - inter;
                bool sup = inter > 0.601f * denom;
                bool amb = !sup && (inter > 0.599f * denom) && (inter > 0.0f);
                if (__any(amb)) {               // rare: exact f64, div-free compare
                    if (amb) {
                        double tl0d = fmax(sb0[i], sb0[j]);
                        double tl1d = fmax(sb1[i], sb1[j]);
                        double br0d = fmin(sb2[i], sb2[j]);
                        double br1d = fmin(sb3[i], sb3[j]);
                        double wh0d = br0d - tl0d; if (wh0d < 0.0) wh0d = 0.0;
                        double wh1d = br1d - tl1d; if (wh1d < 0.0) wh1d = 0.0;
                        double interd = wh0d * wh1d;
                        double denomd = ((sarea[i] + sarea[j]) - interd) + 1e-9;
                        sup = interd > 0.6 * denomd;
                    }
                }
                if (sup) m |= 1ull << (j - jbase);
            }
        }
        supmask[i][w] = m;
    }
    __syncthreads();

    // ---- serial greedy scan over bitmasks
    if (tid == 0) {
        unsigned long long kp0 = ~0ull, kp1 = ~0ull;
        for (int i = 0; i < TOPK; ++i) {
            bool kb = (i < 64) ? ((kp0 >> i) & 1ull) : ((kp1 >> (i - 64)) & 1ull);
            if (kb && svalid[i]) { kp0 &= ~supmask[i][0]; kp1 &= ~supmask[i][1]; }
        }
        keepw[0] = kp0; keepw[1] = kp1;
    }
    __syncthreads();

    // ---- write 5 floats per slot
    if (tid < TOPK) {
        bool kb = (tid < 64) ? ((keepw[0] >> tid) & 1ull)
                             : ((keepw[1] >> (tid - 64)) & 1ull);
        bool kp = kb && (svalid[tid] != 0);
        size_t base = ((size_t)task * TOPK + tid) * 5;
        out[base + 0] = kp ? (float)sb0[tid] : 0.0f;
        out[base + 1] = kp ? (float)sb1[tid] : 0.0f;
        out[base + 2] = kp ? (float)sb2[tid] : 0.0f;
        out[base + 3] = kp ? (float)sb3[tid] : 0.0f;
        out[base + 4] = kp ? (float)sscore[tid] : 0.0f;
    }
}

extern "C" void kernel_launch(void* const* d_in, const int* in_sizes, int n_in,
                              void* d_out, int out_size, void* d_ws, size_t ws_size,
                              hipStream_t stream) {
    const float* logits = (const float*)d_in[0];
    const float* boxreg = (const float*)d_in[1];
    const float* priors = (const float*)d_in[2];
    float* out = (float*)d_out;

    const size_t need = (size_t)B_N * NCLS * A_N * sizeof(unsigned);  // 89.4 MB
    if (ws_size >= need) {
        unsigned* keysw = (unsigned*)d_ws;
        const int NT = (A_N + TA - 1) / TA;
        key_transpose_kernel<<<dim3(B_N * NT), dim3(NTHR), 0, stream>>>(logits, keysw);
        ssd_nms_kernel<true><<<dim3(NTASK), dim3(NTHR), 0, stream>>>(
            logits, keysw, boxreg, priors, out);
    } else {
        ssd_nms_kernel<false><<<dim3(NTASK), dim3(NTHR), 0, stream>>>(
            logits, nullptr, boxreg, priors, out);
    }
}

// Round 7
// 102.577 us; speedup vs baseline: 1.2354x; 1.2354x over previous
//
#include <hip/hip_runtime.h>
#include <math.h>

#define A_N   8732
#define A_PAD 8736            // A_N rounded up to 8 (u16 pad, zeros)
#define C_N   81
#define B_N   32
#define NCLS  80
#define NTASK (B_N * NCLS)
#define TOPK  100
#define NTHR  256
#define BINS  2048
#define CAND  512
#define TA    64
#define NV4K  (A_PAD / 8)     // 1092 uint4 (8 u16 keys each) per key row
#define KPT16 5               // ceil(NV4K / NTHR)

// ln(3/7) in f64: sigmoid_f64(x) > 0.3  <=>  x > THR_LOGIT
#define THR_LOGIT (-0.8472978603872034)

// ---- LDS layout (byte offsets; disjoint lifetimes overlaid) ----
#define OFF_HIST   0          // unsigned hist[2048]        0..8192   (dead after cutoff)
#define OFF_SB0    0          // double sb0[100]            (overlays hist)
#define OFF_SB1    800
#define OFF_SB2    1600
#define OFF_SB3    2400
#define OFF_SAREA  3200       // ..4000
#define OFF_SUP    4000       // u64 supmask[100][2]        ..5600
#define OFF_KEEPW  5600       // u64 keepw[2]               ..5616
#define OFF_CAND   8192       // u64 cand[512]              ..12288  (dead after rank)
#define OFF_FB0    8192       // float fb0[100]             (overlays cand)
#define OFF_FB1    8592
#define OFF_FB2    8992
#define OFF_FB3    9392
#define OFF_FAREA  9792
#define OFF_FSC    10192
#define OFF_SVAL   10592      // int svalid[100]            ..10992
#define OFF_CANDI  12288      // unsigned candi[512]        ..14336  (dead after B2)
#define OFF_SSEL   14336      // u64 ssel[100]              ..15136
#define OFF_WTOT   15136      // unsigned wtot[4]
#define OFF_SCAL   15152      // int scal[2]
#define SMEM_SZ    15168

// Monotone map: float bits -> unsigned, order-preserving. 0 = invalid sentinel.
__device__ __forceinline__ unsigned mapf(float x) {
    unsigned b = __float_as_uint(x);
    return b ^ ((b & 0x80000000u) ? 0xFFFFFFFFu : 0x80000000u);
}
__device__ __forceinline__ float unmapf(unsigned u) {
    unsigned b = (u & 0x80000000u) ? (u ^ 0x80000000u) : ~u;
    return __uint_as_float(b);
}

// ---- Kernel T: coalesced logits read, u16 keys transposed to (B, 80, A_PAD) ----
__global__ __launch_bounds__(NTHR) void key_transpose_kernel(
    const float* __restrict__ logits,          // (B, A, 81)
    unsigned short* __restrict__ keys)         // (B, 80, A_PAD) u16
{
    __shared__ unsigned short tile[NCLS][TA + 2];   // 80 x 66 u16 = 10.3 KB
    const int NT = (A_N + TA - 1) / TA;             // 137
    const int b  = blockIdx.x / NT;
    const int t0 = blockIdx.x % NT;
    const int a0 = t0 * TA;
    const int an = min(TA, A_N - a0);
    const int tid = threadIdx.x;

    const float* src = logits + ((size_t)b * A_N + a0) * C_N;

    if (an == TA) {
        const float4* src4 = (const float4*)src;
        const int total4 = TA * C_N / 4;            // 1296
        for (int i = tid; i < total4; i += NTHR) {
            float4 v = src4[i];
            int base = 4 * i;
            int r  = base / C_N;
            int ch = base - r * C_N;
            float xs[4] = { v.x, v.y, v.z, v.w };
            #pragma unroll
            for (int k = 0; k < 4; ++k) {
                if (ch > 0)
                    tile[ch - 1][r] = (unsigned short)
                        (((double)xs[k] > THR_LOGIT) ? (mapf(xs[k]) >> 16) : 0u);
                if (++ch == C_N) { ch = 0; ++r; }
            }
        }
        __syncthreads();
        // write out: 80 rows x 8 uint4 (each uint4 = 8 u16 keys)
        for (int i = tid; i < NCLS * 8; i += NTHR) {
            int row = i >> 3, j = i & 7;
            const unsigned* t32 = (const unsigned*)&tile[row][8 * j];  // 4B-aligned
            uint4 w;
            w.x = t32[0]; w.y = t32[1]; w.z = t32[2]; w.w = t32[3];
            *(uint4*)(keys + ((size_t)(b * NCLS + row)) * A_PAD + a0 + 8 * j) = w;
        }
    } else {
        const int total = an * C_N;
        for (int i = tid; i < total; i += NTHR) {
            int r = i / C_N, ch = i - r * C_N;
            float x = src[i];
            if (ch > 0)
                tile[ch - 1][r] = (unsigned short)
                    (((double)x > THR_LOGIT) ? (mapf(x) >> 16) : 0u);
        }
        __syncthreads();
        for (int i = tid; i < NCLS * TA; i += NTHR) {
            int row = i / TA, col = i - row * TA;
            int a = a0 + col;
            if (a < A_PAD)
                keys[((size_t)(b * NCLS + row)) * A_PAD + a] =
                    (col < an) ? tile[row][col] : (unsigned short)0;
        }
    }
}

// ---- Kernel M: one task per block ----
template<bool USE_WS>
__global__ __launch_bounds__(NTHR) void ssd_nms_kernel(
    const float* __restrict__ logits,
    const unsigned short* __restrict__ keys,
    const float* __restrict__ boxreg,
    const float* __restrict__ priors,
    float* __restrict__ out)
{
    const int task = blockIdx.x;
    const int b = task / NCLS;
    const int c = task % NCLS;
    const int tid = threadIdx.x;

    __shared__ __align__(16) char smem[SMEM_SZ];
    unsigned* hist  = (unsigned*)(smem + OFF_HIST);
    unsigned long long* cand  = (unsigned long long*)(smem + OFF_CAND);
    unsigned* candi = (unsigned*)(smem + OFF_CANDI);
    unsigned long long* ssel  = (unsigned long long*)(smem + OFF_SSEL);
    unsigned* wtot  = (unsigned*)(smem + OFF_WTOT);
    int* scal       = (int*)(smem + OFF_SCAL);
    double* sb0 = (double*)(smem + OFF_SB0);
    double* sb1 = (double*)(smem + OFF_SB1);
    double* sb2 = (double*)(smem + OFF_SB2);
    double* sb3 = (double*)(smem + OFF_SB3);
    double* sarea = (double*)(smem + OFF_SAREA);
    unsigned long long (*supmask)[2] = (unsigned long long (*)[2])(smem + OFF_SUP);
    unsigned long long* keepw = (unsigned long long*)(smem + OFF_KEEPW);
    float* fb0 = (float*)(smem + OFF_FB0);
    float* fb1 = (float*)(smem + OFF_FB1);
    float* fb2 = (float*)(smem + OFF_FB2);
    float* fb3 = (float*)(smem + OFF_FB3);
    float* farea = (float*)(smem + OFF_FAREA);
    float* fscore = (float*)(smem + OFF_FSC);
    int* svalid = (int*)(smem + OFF_SVAL);

    const float* lg = logits + ((size_t)b * A_N * C_N) + (c + 1);

    // ---- issue key loads up front (5 independent uint4 per thread)
    uint4 kreg[KPT16];
    if (USE_WS) {
        const uint4* src = (const uint4*)(keys + (size_t)(b * NCLS + c) * A_PAD);
        #pragma unroll
        for (int j = 0; j < KPT16; ++j) {
            int i = tid + j * NTHR;
            kreg[j] = (i < NV4K) ? src[i] : make_uint4(0u, 0u, 0u, 0u);
        }
    }

    for (int k = tid; k < BINS; k += NTHR) hist[k] = 0;
    for (int i = tid; i < CAND; i += NTHR) cand[i] = 0ull;
    if (tid < TOPK) ssel[tid] = 0ull;
    if (tid == 0) { scal[0] = 0; scal[1] = 1; }
    __syncthreads();

    // ---- Pass A: 2048-bin histogram (bin = u16 key >> 5)
    if (USE_WS) {
        #pragma unroll
        for (int j = 0; j < KPT16; ++j) {
            uint4 v = kreg[j];
            unsigned w, k;
            w = v.x; k = w & 0xFFFFu; if (k) atomicAdd(&hist[k >> 5], 1u);
                     k = w >> 16;     if (k) atomicAdd(&hist[k >> 5], 1u);
            w = v.y; k = w & 0xFFFFu; if (k) atomicAdd(&hist[k >> 5], 1u);
                     k = w >> 16;     if (k) atomicAdd(&hist[k >> 5], 1u);
            w = v.z; k = w & 0xFFFFu; if (k) atomicAdd(&hist[k >> 5], 1u);
                     k = w >> 16;     if (k) atomicAdd(&hist[k >> 5], 1u);
            w = v.w; k = w & 0xFFFFu; if (k) atomicAdd(&hist[k >> 5], 1u);
                     k = w >> 16;     if (k) atomicAdd(&hist[k >> 5], 1u);
        }
    } else {
        for (int a = tid; a < A_N; a += NTHR) {
            float x = lg[(size_t)a * C_N];
            if ((double)x > THR_LOGIT) atomicAdd(&hist[mapf(x) >> 21], 1u);
        }
    }
    __syncthreads();

    // ---- cutoff: wave-level suffix scan over bins (2 barriers)
    {
        unsigned s = 0;
        #pragma unroll
        for (int k = 0; k < BINS / NTHR; ++k) s += hist[tid * (BINS / NTHR) + k];
        unsigned incl = s;
        int lane = tid & 63;
        #pragma unroll
        for (int off = 1; off < 64; off <<= 1) {
            unsigned v = __shfl_down(incl, off);
            if (lane + off < 64) incl += v;
        }
        if (lane == 0) wtot[tid >> 6] = incl;
        __syncthreads();
        unsigned hi = 0;
        #pragma unroll
        for (int w = 0; w < 4; ++w) if (w > (tid >> 6)) hi += wtot[w];
        unsigned excl = hi + (incl - s);
        if (excl < TOPK && excl + s >= TOPK) {
            unsigned running = excl;
            #pragma unroll
            for (int k = BINS / NTHR - 1; k >= 0; --k) {
                running += hist[tid * (BINS / NTHR) + k];
                if (running >= TOPK) {
                    scal[1] = (int)(((unsigned)(tid * (BINS / NTHR) + k)) << 5);
                    break;
                }
            }
        }
    }
    __syncthreads();
    const unsigned cut16 = (unsigned)scal[1];   // u16 granularity, >= 1

    // ---- Pass B1: gather candidate ANCHOR INDICES (k16 >= cut16)
    if (USE_WS) {
        #pragma unroll
        for (int j = 0; j < KPT16; ++j) {
            uint4 v = kreg[j];
            int a8 = 8 * (tid + j * NTHR);
            unsigned w, k; int p;
            w = v.x;
            k = w & 0xFFFFu; if (k >= cut16) { p = atomicAdd(&scal[0], 1); if (p < CAND) candi[p] = (unsigned)(a8 + 0); }
            k = w >> 16;     if (k >= cut16) { p = atomicAdd(&scal[0], 1); if (p < CAND) candi[p] = (unsigned)(a8 + 1); }
            w = v.y;
            k = w & 0xFFFFu; if (k >= cut16) { p = atomicAdd(&scal[0], 1); if (p < CAND) candi[p] = (unsigned)(a8 + 2); }
            k = w >> 16;     if (k >= cut16) { p = atomicAdd(&scal[0], 1); if (p < CAND) candi[p] = (unsigned)(a8 + 3); }
            w = v.z;
            k = w & 0xFFFFu; if (k >= cut16) { p = atomicAdd(&scal[0], 1); if (p < CAND) candi[p] = (unsigned)(a8 + 4); }
            k = w >> 16;     if (k >= cut16) { p = atomicAdd(&scal[0], 1); if (p < CAND) candi[p] = (unsigned)(a8 + 5); }
            w = v.w;
            k = w & 0xFFFFu; if (k >= cut16) { p = atomicAdd(&scal[0], 1); if (p < CAND) candi[p] = (unsigned)(a8 + 6); }
            k = w >> 16;     if (k >= cut16) { p = atomicAdd(&scal[0], 1); if (p < CAND) candi[p] = (unsigned)(a8 + 7); }
        }
    } else {
        const unsigned cut32 = cut16 << 16;
        for (int a = tid; a < A_N; a += NTHR) {
            float x = lg[(size_t)a * C_N];
            if ((double)x > THR_LOGIT) {
                unsigned u = mapf(x);
                if (u >= cut32) {
                    int p = atomicAdd(&scal[0], 1);
                    if (p < CAND) candi[p] = (unsigned)a;
                }
            }
        }
    }
    __syncthreads();
    const int M = min(scal[0], CAND);

    // ---- Pass B2: rebuild full-precision keys for the ~M candidates (L3 hits)
    for (int i = tid; i < M; i += NTHR) {
        unsigned a = candi[i];
        float x = lg[(size_t)a * C_N];
        cand[i] = ((unsigned long long)mapf(x) << 32) | (unsigned)(~a);
    }
    __syncthreads();

    // ---- exact rank via all-pairs (order-independent, broadcast reads)
    {
        int Mr = (M + 7) & ~7;
        for (int i = tid; i < Mr; i += NTHR) {
            unsigned long long mykey = cand[i];
            int rank = 0;
            #pragma unroll 8
            for (int j = 0; j < Mr; ++j) rank += (cand[j] > mykey) ? 1 : 0;
            if (mykey != 0ull && rank < TOPK) ssel[rank] = mykey;
        }
    }
    __syncthreads();

    // ---- decode top-100 boxes in f64 (reference op order); store f64 + f32 shadows
    if (tid < TOPK) {
        unsigned long long key = ssel[tid];
        int valid = (key != 0ull);
        double b0 = 0, b1 = 0, b2 = 0, b3 = 0, area = 0, sc = 0;
        if (valid) {
            int a = (int)(~(unsigned)key);
            float x = unmapf((unsigned)(key >> 32));
            sc = 1.0 / (1.0 + exp(-(double)x));
            float4 r4 = *(const float4*)(boxreg + ((size_t)b * A_N + a) * 4);
            float4 p4 = *(const float4*)(priors + (size_t)a * 4);
            double ty = (double)r4.x / 10.0;
            double tx = (double)r4.y / 10.0;
            double th = (double)r4.z / 5.0;
            double tw = (double)r4.w / 5.0;
            double py = (double)p4.x, px = (double)p4.y;
            double ph = (double)p4.z, pw = (double)p4.w;
            double cy = ty * ph + py;
            double cx = tx * pw + px;
            double hh = exp(th) * ph;
            double ww = exp(tw) * pw;
            b0 = cy - hh / 2.0; b1 = cx - ww / 2.0;
            b2 = cy + hh / 2.0; b3 = cx + ww / 2.0;
            double e0 = b2 - b0; if (e0 < 0.0) e0 = 0.0;
            double e1 = b3 - b1; if (e1 < 0.0) e1 = 0.0;
            area = e0 * e1;
        }
        sb0[tid] = b0; sb1[tid] = b1; sb2[tid] = b2; sb3[tid] = b3;
        sarea[tid] = area;
        fb0[tid] = (float)b0; fb1[tid] = (float)b1;
        fb2[tid] = (float)b2; fb3[tid] = (float)b3;
        farea[tid] = (float)area;
        fscore[tid] = (float)sc;
        svalid[tid] = valid;
    }
    __syncthreads();

    // ---- suppression bitmask: f32 screen, exact-f64 recheck in ambiguous window
    if (tid < 2 * TOPK) {
        int i = tid >> 1, w = tid & 1;
        unsigned long long m = 0;
        if (svalid[i]) {
            float i0 = fb0[i], i1 = fb1[i], i2 = fb2[i], i3 = fb3[i], ia = farea[i];
            int jbase = w * 64;
            int jend = min(jbase + 64, TOPK);
            int jstart = (jbase > i + 1) ? jbase : (i + 1);
            for (int j = jstart; j < jend; ++j) {
                float tl0 = fmaxf(i0, fb0[j]);
                float tl1 = fmaxf(i1, fb1[j]);
                float br0 = fminf(i2, fb2[j]);
                float br1 = fminf(i3, fb3[j]);
                float wh0 = fmaxf(br0 - tl0, 0.0f);
                float wh1 = fmaxf(br1 - tl1, 0.0f);
                float inter = wh0 * wh1;
                float denom = (ia + farea[j]) - inter;
                bool sup = inter > 0.601f * denom;
                bool amb = !sup && (inter > 0.599f * denom) && (inter > 0.0f);
                if (__any(amb)) {
                    if (amb) {
                        double tl0d = fmax(sb0[i], sb0[j]);
                        double tl1d = fmax(sb1[i], sb1[j]);
                        double br0d = fmin(sb2[i], sb2[j]);
                        double br1d = fmin(sb3[i], sb3[j]);
                        double wh0d = br0d - tl0d; if (wh0d < 0.0) wh0d = 0.0;
                        double wh1d = br1d - tl1d; if (wh1d < 0.0) wh1d = 0.0;
                        double interd = wh0d * wh1d;
                        double denomd = ((sarea[i] + sarea[j]) - interd) + 1e-9;
                        sup = interd > 0.6 * denomd;
                    }
                }
                if (sup) m |= 1ull << (j - jbase);
            }
        }
        supmask[i][w] = m;
    }
    __syncthreads();

    // ---- serial greedy scan over bitmasks
    if (tid == 0) {
        unsigned long long kp0 = ~0ull, kp1 = ~0ull;
        for (int i = 0; i < TOPK; ++i) {
            bool kb = (i < 64) ? ((kp0 >> i) & 1ull) : ((kp1 >> (i - 64)) & 1ull);
            if (kb && svalid[i]) { kp0 &= ~supmask[i][0]; kp1 &= ~supmask[i][1]; }
        }
        keepw[0] = kp0; keepw[1] = kp1;
    }
    __syncthreads();

    // ---- write 5 floats per slot
    if (tid < TOPK) {
        bool kb = (tid < 64) ? ((keepw[0] >> tid) & 1ull)
                             : ((keepw[1] >> (tid - 64)) & 1ull);
        bool kp = kb && (svalid[tid] != 0);
        size_t base = ((size_t)task * TOPK + tid) * 5;
        out[base + 0] = kp ? fb0[tid] : 0.0f;
        out[base + 1] = kp ? fb1[tid] : 0.0f;
        out[base + 2] = kp ? fb2[tid] : 0.0f;
        out[base + 3] = kp ? fb3[tid] : 0.0f;
        out[base + 4] = kp ? fscore[tid] : 0.0f;
    }
}

extern "C" void kernel_launch(void* const* d_in, const int* in_sizes, int n_in,
                              void* d_out, int out_size, void* d_ws, size_t ws_size,
                              hipStream_t stream) {
    const float* logits = (const float*)d_in[0];
    const float* boxreg = (const float*)d_in[1];
    const float* priors = (const float*)d_in[2];
    float* out = (float*)d_out;

    const size_t need = (size_t)NTASK * A_PAD * sizeof(unsigned short);  // 44.7 MB
    if (ws_size >= need) {
        unsigned short* keysw = (unsigned short*)d_ws;
        const int NT = (A_N + TA - 1) / TA;
        key_transpose_kernel<<<dim3(B_N * NT), dim3(NTHR), 0, stream>>>(logits, keysw);
        ssd_nms_kernel<true><<<dim3(NTASK), dim3(NTHR), 0, stream>>>(
            logits, keysw, boxreg, priors, out);
    } else {
        ssd_nms_kernel<false><<<dim3(NTASK), dim3(NTHR), 0, stream>>>(
            logits, nullptr, boxreg, priors, out);
    }
}